// Round 1
// baseline (1271.508 us; speedup 1.0000x reference)
//
#include <hip/hip_runtime.h>
#include <hip/hip_bf16.h>
#include <stdint.h>

// TinyMoE: T=8192 tokens, D=1024, H=4096, E=8, top-2.
// Strategy: route -> compact per-expert lists (padded to 128) -> two grouped
// bf16 MFMA GEMMs (m97 128x128 structure) with gather on A (pass1) and
// atomic scatter on C (pass2).

#define T_TOK 8192
#define D_DIM 1024
#define H_DIM 4096
#define NEXP  8
#define ROWCAP (T_TOK*2 + NEXP*128)   // 17408, multiple of 128

typedef short s16x8 __attribute__((ext_vector_type(8)));
typedef float f32x4 __attribute__((ext_vector_type(4)));

__device__ __forceinline__ unsigned short f2bf(float v) {
    __hip_bfloat16 b = __float2bfloat16(v);
    return __builtin_bit_cast(unsigned short, b);
}

__device__ __forceinline__ void gl_lds16(const unsigned short* g, unsigned short* l) {
    __builtin_amdgcn_global_load_lds((const __attribute__((address_space(1))) void*)g,
                                     (__attribute__((address_space(3))) void*)l, 16, 0, 0);
}

// ---------------- conversion kernels ----------------

__global__ __launch_bounds__(256) void convx_kernel(const float* __restrict__ x,
                                                    unsigned short* __restrict__ xbf) {
    int i = blockIdx.x * 256 + threadIdx.x;      // grid covers T*D/4 exactly
    float4 v = ((const float4*)x)[i];
    ushort4 o;
    o.x = f2bf(v.x); o.y = f2bf(v.y); o.z = f2bf(v.z); o.w = f2bf(v.w);
    ((ushort4*)xbf)[i] = o;
}

// src: [z][R][C] fp32 -> dst: [z][C][R] bf16   (block (32,8), grid (C/32, R/32, z))
__global__ __launch_bounds__(256) void convt_kernel(const float* __restrict__ src,
                                                    unsigned short* __restrict__ dst,
                                                    int R, int C) {
    __shared__ float tile[32][33];
    size_t mat = (size_t)R * C;
    const float* s = src + (size_t)blockIdx.z * mat;
    unsigned short* d = dst + (size_t)blockIdx.z * mat;
    int c0 = blockIdx.x << 5, r0 = blockIdx.y << 5;
    int tx = threadIdx.x, ty = threadIdx.y;
#pragma unroll
    for (int i = 0; i < 4; i++)
        tile[ty + 8*i][tx] = s[(size_t)(r0 + ty + 8*i) * C + c0 + tx];
    __syncthreads();
#pragma unroll
    for (int i = 0; i < 4; i++)
        d[(size_t)(c0 + ty + 8*i) * R + r0 + tx] = f2bf(tile[tx][ty + 8*i]);
}

// ---------------- routing ----------------

// one wave per token; lane = 8*g + e; lane accumulates expert e over d = g mod 8
__global__ __launch_bounds__(256) void router_kernel(const float* __restrict__ x,
                                                     const float* __restrict__ wr,
                                                     const float* __restrict__ br,
                                                     int* __restrict__ counts,
                                                     int* __restrict__ te,
                                                     float* __restrict__ tg) {
    int wid = threadIdx.x >> 6, lane = threadIdx.x & 63;
    int t = blockIdx.x * 4 + wid;
    int g = lane >> 3;
    const float* xr = x + (size_t)t * D_DIM;
    float acc = 0.f;
#pragma unroll 8
    for (int j = 0; j < 128; j++)
        acc += xr[g + 8*j] * wr[lane + 64*j];    // wr[(g+8j)*8 + e] == wr[lane + 64j]
    acc += __shfl_xor(acc, 8);
    acc += __shfl_xor(acc, 16);
    acc += __shfl_xor(acc, 32);
    float lg[8];
#pragma unroll
    for (int q = 0; q < 8; q++) lg[q] = __shfl(acc, q) + br[q];
    if (lane == 0) {
        float mx = lg[0];
#pragma unroll
        for (int q = 1; q < 8; q++) mx = fmaxf(mx, lg[q]);
        float p[8], s = 0.f;
#pragma unroll
        for (int q = 0; q < 8; q++) { p[q] = __expf(lg[q] - mx); s += p[q]; }
        int i1 = 0;
#pragma unroll
        for (int q = 1; q < 8; q++) if (p[q] > p[i1]) i1 = q;
        int i2 = (i1 == 0) ? 1 : 0;
#pragma unroll
        for (int q = 0; q < 8; q++) if (q != i1 && p[q] > p[i2]) i2 = q;
        float inv = 1.f / s;
        atomicAdd(&counts[i1], 1);
        atomicAdd(&counts[i2], 1);
        te[t] = i1;          tg[t] = p[i1] * inv;
        te[T_TOK + t] = i2;  tg[T_TOK + t] = p[i2] * inv;
    }
}

__global__ void offsets_kernel(const int* __restrict__ counts, int* __restrict__ poff) {
    if (threadIdx.x == 0 && blockIdx.x == 0) {
        int acc = 0; poff[0] = 0;
#pragma unroll
        for (int e = 0; e < 8; e++) { acc += (counts[e] + 127) & ~127; poff[e + 1] = acc; }
    }
}

__global__ __launch_bounds__(256) void scatter_kernel(const int* __restrict__ te,
                                                      const float* __restrict__ tg,
                                                      int* __restrict__ counts2,
                                                      const int* __restrict__ poff,
                                                      int* __restrict__ list,
                                                      float* __restrict__ gate) {
    int i = blockIdx.x * 256 + threadIdx.x;
    if (i >= 2 * T_TOK) return;
    int e = te[i];
    int slot = atomicAdd(&counts2[e], 1);
    int gidx = poff[e] + slot;
    list[gidx] = i & (T_TOK - 1);
    gate[gidx] = tg[i];
}

// ---------------- grouped GEMMs (m97 128x128x64 structure) ----------------

// pass1: h[slot][H] = relu(gather(xbf)[slot] @ w1t[e]^T + b1[e]); A,B rows k-contig.
__global__ __launch_bounds__(256) void ffn1_kernel(const unsigned short* __restrict__ xbf,
                                                   const unsigned short* __restrict__ w1t,
                                                   const float* __restrict__ b1,
                                                   unsigned short* __restrict__ hbuf,
                                                   const int* __restrict__ list,
                                                   const int* __restrict__ poff) {
    __shared__ unsigned short As[128 * 64];
    __shared__ unsigned short Bs[128 * 64];
    int row0 = blockIdx.x << 7;
    if (row0 >= poff[8]) return;
    int e = 0;
#pragma unroll
    for (int i = 1; i < 8; i++) e += (row0 >= poff[i]);
    const unsigned short* Bp = w1t + (size_t)e * D_DIM * H_DIM;
    int n0 = blockIdx.y << 7;
    int tid = threadIdx.x, lane = tid & 63, wid = tid >> 6;
    int wm = wid >> 1, wn = wid & 1;

    const unsigned short* asrc[4];
    const unsigned short* bsrc[4];
#pragma unroll
    for (int i = 0; i < 4; i++) {
        int lin = tid + (i << 8);
        int r = lin >> 3, kc = lin & 7;
        int tok = list[row0 + r];
        asrc[i] = xbf + (size_t)tok * D_DIM + kc * 8;
        bsrc[i] = Bp + (size_t)(n0 + r) * D_DIM + kc * 8;
    }
    f32x4 acc[4][4] = {};
    for (int k0 = 0; k0 < D_DIM; k0 += 64) {
        __syncthreads();
#pragma unroll
        for (int i = 0; i < 4; i++) {
            int lin = tid + (i << 8);
            gl_lds16(asrc[i] + k0, As + lin * 8);
            gl_lds16(bsrc[i] + k0, Bs + lin * 8);
        }
        __syncthreads();
#pragma unroll
        for (int kk = 0; kk < 64; kk += 32) {
            s16x8 af[4], bf_[4];
#pragma unroll
            for (int m = 0; m < 4; m++)
                af[m] = *(const s16x8*)(As + ((wm*64 + m*16 + (lane & 15)) * 64 + kk + (lane >> 4) * 8));
#pragma unroll
            for (int n = 0; n < 4; n++)
                bf_[n] = *(const s16x8*)(Bs + ((wn*64 + n*16 + (lane & 15)) * 64 + kk + (lane >> 4) * 8));
#pragma unroll
            for (int m = 0; m < 4; m++)
#pragma unroll
                for (int n = 0; n < 4; n++)
                    acc[m][n] = __builtin_amdgcn_mfma_f32_16x16x32_bf16(af[m], bf_[n], acc[m][n], 0, 0, 0);
        }
    }
#pragma unroll
    for (int m = 0; m < 4; m++) {
        int rbase = row0 + wm*64 + m*16 + ((lane >> 4) << 2);
#pragma unroll
        for (int n = 0; n < 4; n++) {
            int c = n0 + wn*64 + n*16 + (lane & 15);
            float bias = b1[e * H_DIM + c];
#pragma unroll
            for (int j = 0; j < 4; j++) {
                float v = fmaxf(acc[m][n][j] + bias, 0.0f);
                hbuf[(size_t)(rbase + j) * H_DIM + c] = f2bf(v);
            }
        }
    }
}

// pass2: out[tok] += gate * (h[slot] @ w2t[e]^T + b2[e])
__global__ __launch_bounds__(256) void ffn2_kernel(const unsigned short* __restrict__ hbuf,
                                                   const unsigned short* __restrict__ w2t,
                                                   const float* __restrict__ b2,
                                                   float* __restrict__ out,
                                                   const int* __restrict__ list,
                                                   const float* __restrict__ gate,
                                                   const int* __restrict__ poff) {
    __shared__ unsigned short As[128 * 64];
    __shared__ unsigned short Bs[128 * 64];
    int row0 = blockIdx.x << 7;
    if (row0 >= poff[8]) return;
    int e = 0;
#pragma unroll
    for (int i = 1; i < 8; i++) e += (row0 >= poff[i]);
    const unsigned short* Bp = w2t + (size_t)e * D_DIM * H_DIM;
    int n0 = blockIdx.y << 7;
    int tid = threadIdx.x, lane = tid & 63, wid = tid >> 6;
    int wm = wid >> 1, wn = wid & 1;

    const unsigned short* asrc[4];
    const unsigned short* bsrc[4];
#pragma unroll
    for (int i = 0; i < 4; i++) {
        int lin = tid + (i << 8);
        int r = lin >> 3, kc = lin & 7;
        asrc[i] = hbuf + (size_t)(row0 + r) * H_DIM + kc * 8;
        bsrc[i] = Bp + (size_t)(n0 + r) * H_DIM + kc * 8;
    }
    f32x4 acc[4][4] = {};
    for (int k0 = 0; k0 < H_DIM; k0 += 64) {
        __syncthreads();
#pragma unroll
        for (int i = 0; i < 4; i++) {
            int lin = tid + (i << 8);
            gl_lds16(asrc[i] + k0, As + lin * 8);
            gl_lds16(bsrc[i] + k0, Bs + lin * 8);
        }
        __syncthreads();
#pragma unroll
        for (int kk = 0; kk < 64; kk += 32) {
            s16x8 af[4], bf_[4];
#pragma unroll
            for (int m = 0; m < 4; m++)
                af[m] = *(const s16x8*)(As + ((wm*64 + m*16 + (lane & 15)) * 64 + kk + (lane >> 4) * 8));
#pragma unroll
            for (int n = 0; n < 4; n++)
                bf_[n] = *(const s16x8*)(Bs + ((wn*64 + n*16 + (lane & 15)) * 64 + kk + (lane >> 4) * 8));
#pragma unroll
            for (int m = 0; m < 4; m++)
#pragma unroll
                for (int n = 0; n < 4; n++)
                    acc[m][n] = __builtin_amdgcn_mfma_f32_16x16x32_bf16(af[m], bf_[n], acc[m][n], 0, 0, 0);
        }
    }
#pragma unroll
    for (int m = 0; m < 4; m++) {
#pragma unroll
        for (int j = 0; j < 4; j++) {
            int srow = row0 + wm*64 + m*16 + ((lane >> 4) << 2) + j;
            float g = gate[srow];
            if (g != 0.0f) {
                int tok = list[srow];
#pragma unroll
                for (int n = 0; n < 4; n++) {
                    int c = n0 + wn*64 + n*16 + (lane & 15);
                    float v = g * (acc[m][n][j] + b2[e * D_DIM + c]);
                    atomicAdd(&out[(size_t)tok * D_DIM + c], v);
                }
            }
        }
    }
}

// ---------------- host ----------------

extern "C" void kernel_launch(void* const* d_in, const int* in_sizes, int n_in,
                              void* d_out, int out_size, void* d_ws, size_t ws_size,
                              hipStream_t stream) {
    const float* x  = (const float*)d_in[0];
    const float* wr = (const float*)d_in[1];
    const float* br = (const float*)d_in[2];
    const float* w1 = (const float*)d_in[3];
    const float* b1 = (const float*)d_in[4];
    const float* w2 = (const float*)d_in[5];
    const float* b2 = (const float*)d_in[6];
    float* out = (float*)d_out;
    (void)in_sizes; (void)n_in; (void)ws_size;

    char* ws = (char*)d_ws;
    size_t off = 0;
    auto alloc = [&](size_t bytes) { size_t o = off; off = (off + bytes + 1023) & ~(size_t)1023; return o; };
    size_t o_meta = alloc(256);                         // counts[8], counts2[8], poff[16]
    size_t o_list = alloc((size_t)ROWCAP * 4);
    size_t o_gate = alloc((size_t)ROWCAP * 4);
    size_t o_te   = alloc((size_t)2 * T_TOK * 4);
    size_t o_tg   = alloc((size_t)2 * T_TOK * 4);
    size_t o_xbf  = alloc((size_t)T_TOK * D_DIM * 2);
    size_t o_w1t  = alloc((size_t)NEXP * D_DIM * H_DIM * 2);
    size_t o_w2t  = alloc((size_t)NEXP * D_DIM * H_DIM * 2);
    size_t o_h    = alloc((size_t)ROWCAP * H_DIM * 2);

    int* counts  = (int*)(ws + o_meta);
    int* counts2 = counts + 8;
    int* poff    = counts + 16;
    int* list    = (int*)(ws + o_list);
    float* gate  = (float*)(ws + o_gate);
    int* te      = (int*)(ws + o_te);
    float* tg    = (float*)(ws + o_tg);
    unsigned short* xbf = (unsigned short*)(ws + o_xbf);
    unsigned short* w1t = (unsigned short*)(ws + o_w1t);
    unsigned short* w2t = (unsigned short*)(ws + o_w2t);
    unsigned short* hbuf = (unsigned short*)(ws + o_h);

    hipMemsetAsync(ws + o_meta, 0, 256, stream);
    hipMemsetAsync(ws + o_list, 0, (size_t)ROWCAP * 4, stream);   // token 0
    hipMemsetAsync(ws + o_gate, 0, (size_t)ROWCAP * 4, stream);   // gate 0.0
    hipMemsetAsync(d_out, 0, (size_t)out_size * 4, stream);

    // conversions
    convx_kernel<<<T_TOK * D_DIM / 4 / 256, 256, 0, stream>>>(x, xbf);
    convt_kernel<<<dim3(H_DIM / 32, D_DIM / 32, NEXP), dim3(32, 8), 0, stream>>>(w1, w1t, D_DIM, H_DIM);
    convt_kernel<<<dim3(D_DIM / 32, H_DIM / 32, NEXP), dim3(32, 8), 0, stream>>>(w2, w2t, H_DIM, D_DIM);

    // routing
    router_kernel<<<T_TOK / 4, 256, 0, stream>>>(x, wr, br, counts, te, tg);
    offsets_kernel<<<1, 64, 0, stream>>>(counts, poff);
    scatter_kernel<<<(2 * T_TOK) / 256, 256, 0, stream>>>(te, tg, counts2, poff, list, gate);

    // grouped GEMMs
    ffn1_kernel<<<dim3(ROWCAP / 128, H_DIM / 128), 256, 0, stream>>>(xbf, w1t, b1, hbuf, list, poff);
    ffn2_kernel<<<dim3(ROWCAP / 128, D_DIM / 128), 256, 0, stream>>>(hbuf, w2t, b2, out, list, gate, poff);
}

// Round 2
// 1108.562 us; speedup vs baseline: 1.1470x; 1.1470x over previous
//
#include <hip/hip_runtime.h>
#include <hip/hip_bf16.h>
#include <stdint.h>

// TinyMoE: T=8192 tokens, D=1024, H=4096, E=8, top-2.
// R2: ffn2 atomics -> ybuf + combine pass; both-sides LDS XOR swizzle on the
// grouped GEMMs (pre-swizzled global_load_lds source + swizzled ds_read).

#define T_TOK 8192
#define D_DIM 1024
#define H_DIM 4096
#define NEXP  8
#define ROWCAP (T_TOK*2 + NEXP*128)   // 17408, multiple of 128

typedef short s16x8 __attribute__((ext_vector_type(8)));
typedef float f32x4 __attribute__((ext_vector_type(4)));

__device__ __forceinline__ unsigned short f2bf(float v) {
    __hip_bfloat16 b = __float2bfloat16(v);
    return __builtin_bit_cast(unsigned short, b);
}

__device__ __forceinline__ void gl_lds16(const unsigned short* g, unsigned short* l) {
    __builtin_amdgcn_global_load_lds((const __attribute__((address_space(1))) void*)g,
                                     (__attribute__((address_space(3))) void*)l, 16, 0, 0);
}

// swizzled fragment read: row-major [128][64] bf16 tile, 16B chunk index XOR'd
// with (row&7). Pairs with source pre-swizzle in the staging address setup.
__device__ __forceinline__ s16x8 lds_frag(const unsigned short* base, int row, int chunk) {
    return *(const s16x8*)(base + row * 64 + ((chunk ^ (row & 7)) << 3));
}

// ---------------- conversion kernels ----------------

__global__ __launch_bounds__(256) void convx_kernel(const float* __restrict__ x,
                                                    unsigned short* __restrict__ xbf) {
    int i = blockIdx.x * 256 + threadIdx.x;      // grid covers T*D/4 exactly
    float4 v = ((const float4*)x)[i];
    ushort4 o;
    o.x = f2bf(v.x); o.y = f2bf(v.y); o.z = f2bf(v.z); o.w = f2bf(v.w);
    ((ushort4*)xbf)[i] = o;
}

// src: [z][R][C] fp32 -> dst: [z][C][R] bf16   (block (32,8), grid (C/32, R/32, z))
__global__ __launch_bounds__(256) void convt_kernel(const float* __restrict__ src,
                                                    unsigned short* __restrict__ dst,
                                                    int R, int C) {
    __shared__ float tile[32][33];
    size_t mat = (size_t)R * C;
    const float* s = src + (size_t)blockIdx.z * mat;
    unsigned short* d = dst + (size_t)blockIdx.z * mat;
    int c0 = blockIdx.x << 5, r0 = blockIdx.y << 5;
    int tx = threadIdx.x, ty = threadIdx.y;
#pragma unroll
    for (int i = 0; i < 4; i++)
        tile[ty + 8*i][tx] = s[(size_t)(r0 + ty + 8*i) * C + c0 + tx];
    __syncthreads();
#pragma unroll
    for (int i = 0; i < 4; i++)
        d[(size_t)(c0 + ty + 8*i) * R + r0 + tx] = f2bf(tile[tx][ty + 8*i]);
}

// ---------------- routing ----------------

// one wave per token; lane = 8*g + e; lane accumulates expert e over d = g mod 8
__global__ __launch_bounds__(256) void router_kernel(const float* __restrict__ x,
                                                     const float* __restrict__ wr,
                                                     const float* __restrict__ br,
                                                     int* __restrict__ counts,
                                                     int* __restrict__ te,
                                                     float* __restrict__ tg) {
    int wid = threadIdx.x >> 6, lane = threadIdx.x & 63;
    int t = blockIdx.x * 4 + wid;
    int g = lane >> 3;
    const float* xr = x + (size_t)t * D_DIM;
    float acc = 0.f;
#pragma unroll 8
    for (int j = 0; j < 128; j++)
        acc += xr[g + 8*j] * wr[lane + 64*j];    // wr[(g+8j)*8 + e] == wr[lane + 64j]
    acc += __shfl_xor(acc, 8);
    acc += __shfl_xor(acc, 16);
    acc += __shfl_xor(acc, 32);
    float lg[8];
#pragma unroll
    for (int q = 0; q < 8; q++) lg[q] = __shfl(acc, q) + br[q];
    if (lane == 0) {
        float mx = lg[0];
#pragma unroll
        for (int q = 1; q < 8; q++) mx = fmaxf(mx, lg[q]);
        float p[8], s = 0.f;
#pragma unroll
        for (int q = 0; q < 8; q++) { p[q] = __expf(lg[q] - mx); s += p[q]; }
        int i1 = 0;
#pragma unroll
        for (int q = 1; q < 8; q++) if (p[q] > p[i1]) i1 = q;
        int i2 = (i1 == 0) ? 1 : 0;
#pragma unroll
        for (int q = 0; q < 8; q++) if (q != i1 && p[q] > p[i2]) i2 = q;
        float inv = 1.f / s;
        atomicAdd(&counts[i1], 1);
        atomicAdd(&counts[i2], 1);
        te[t] = i1;          tg[t] = p[i1] * inv;
        te[T_TOK + t] = i2;  tg[T_TOK + t] = p[i2] * inv;
    }
}

__global__ void offsets_kernel(const int* __restrict__ counts, int* __restrict__ poff) {
    if (threadIdx.x == 0 && blockIdx.x == 0) {
        int acc = 0; poff[0] = 0;
#pragma unroll
        for (int e = 0; e < 8; e++) { acc += (counts[e] + 127) & ~127; poff[e + 1] = acc; }
    }
}

__global__ __launch_bounds__(256) void scatter_kernel(const int* __restrict__ te,
                                                      const float* __restrict__ tg,
                                                      int* __restrict__ counts2,
                                                      const int* __restrict__ poff,
                                                      int* __restrict__ list,
                                                      float* __restrict__ gate,
                                                      int* __restrict__ slotof) {
    int i = blockIdx.x * 256 + threadIdx.x;
    if (i >= 2 * T_TOK) return;
    int e = te[i];
    int slot = atomicAdd(&counts2[e], 1);
    int gidx = poff[e] + slot;
    list[gidx] = i & (T_TOK - 1);
    gate[gidx] = tg[i];
    slotof[i] = gidx;
}

// ---------------- grouped GEMMs (m97 128x128x64 structure, swizzled LDS) ----------------

// pass1: h[slot][H] = relu(gather(xbf)[slot] @ w1t[e]^T + b1[e]); A,B rows k-contig.
__global__ __launch_bounds__(256) void ffn1_kernel(const unsigned short* __restrict__ xbf,
                                                   const unsigned short* __restrict__ w1t,
                                                   const float* __restrict__ b1,
                                                   unsigned short* __restrict__ hbuf,
                                                   const int* __restrict__ list,
                                                   const int* __restrict__ poff) {
    __shared__ unsigned short As[128 * 64];
    __shared__ unsigned short Bs[128 * 64];
    int row0 = blockIdx.x << 7;
    if (row0 >= poff[8]) return;
    int e = 0;
#pragma unroll
    for (int i = 1; i < 8; i++) e += (row0 >= poff[i]);
    const unsigned short* Bp = w1t + (size_t)e * D_DIM * H_DIM;
    int n0 = blockIdx.y << 7;
    int tid = threadIdx.x, lane = tid & 63, wid = tid >> 6;
    int wm = wid >> 1, wn = wid & 1;

    const unsigned short* asrc[4];
    const unsigned short* bsrc[4];
#pragma unroll
    for (int i = 0; i < 4; i++) {
        int lin = tid + (i << 8);
        int r = lin >> 3, kc = lin & 7;
        int sc = kc ^ (r & 7);                       // source pre-swizzle (rule #21)
        int tok = list[row0 + r];
        asrc[i] = xbf + (size_t)tok * D_DIM + sc * 8;
        bsrc[i] = Bp + (size_t)(n0 + r) * D_DIM + sc * 8;
    }
    f32x4 acc[4][4] = {};
    for (int k0 = 0; k0 < D_DIM; k0 += 64) {
        __syncthreads();
#pragma unroll
        for (int i = 0; i < 4; i++) {
            int lin = tid + (i << 8);
            gl_lds16(asrc[i] + k0, As + lin * 8);
            gl_lds16(bsrc[i] + k0, Bs + lin * 8);
        }
        __syncthreads();
#pragma unroll
        for (int kk = 0; kk < 64; kk += 32) {
            s16x8 af[4], bf_[4];
#pragma unroll
            for (int m = 0; m < 4; m++)
                af[m] = lds_frag(As, wm*64 + m*16 + (lane & 15), (kk >> 3) + (lane >> 4));
#pragma unroll
            for (int n = 0; n < 4; n++)
                bf_[n] = lds_frag(Bs, wn*64 + n*16 + (lane & 15), (kk >> 3) + (lane >> 4));
#pragma unroll
            for (int m = 0; m < 4; m++)
#pragma unroll
                for (int n = 0; n < 4; n++)
                    acc[m][n] = __builtin_amdgcn_mfma_f32_16x16x32_bf16(af[m], bf_[n], acc[m][n], 0, 0, 0);
        }
    }
#pragma unroll
    for (int m = 0; m < 4; m++) {
        int rbase = row0 + wm*64 + m*16 + ((lane >> 4) << 2);
#pragma unroll
        for (int n = 0; n < 4; n++) {
            int c = n0 + wn*64 + n*16 + (lane & 15);
            float bias = b1[e * H_DIM + c];
#pragma unroll
            for (int j = 0; j < 4; j++) {
                float v = fmaxf(acc[m][n][j] + bias, 0.0f);
                hbuf[(size_t)(rbase + j) * H_DIM + c] = f2bf(v);
            }
        }
    }
}

// pass2: ybuf[slot] = gate[slot] * (h[slot] @ w2t[e]^T + b2[e])   (no atomics)
__global__ __launch_bounds__(256) void ffn2_kernel(const unsigned short* __restrict__ hbuf,
                                                   const unsigned short* __restrict__ w2t,
                                                   const float* __restrict__ b2,
                                                   float* __restrict__ ybuf,
                                                   const float* __restrict__ gate,
                                                   const int* __restrict__ poff) {
    __shared__ unsigned short As[128 * 64];
    __shared__ unsigned short Bs[128 * 64];
    int row0 = blockIdx.x << 7;
    if (row0 >= poff[8]) return;
    int e = 0;
#pragma unroll
    for (int i = 1; i < 8; i++) e += (row0 >= poff[i]);
    const unsigned short* Bp = w2t + (size_t)e * D_DIM * H_DIM;
    int n0 = blockIdx.y << 7;
    int tid = threadIdx.x, lane = tid & 63, wid = tid >> 6;
    int wm = wid >> 1, wn = wid & 1;

    const unsigned short* asrc[4];
    const unsigned short* bsrc[4];
#pragma unroll
    for (int i = 0; i < 4; i++) {
        int lin = tid + (i << 8);
        int r = lin >> 3, kc = lin & 7;
        int sc = kc ^ (r & 7);                       // source pre-swizzle (rule #21)
        asrc[i] = hbuf + (size_t)(row0 + r) * H_DIM + sc * 8;
        bsrc[i] = Bp + (size_t)(n0 + r) * H_DIM + sc * 8;
    }
    f32x4 acc[4][4] = {};
    for (int k0 = 0; k0 < H_DIM; k0 += 64) {
        __syncthreads();
#pragma unroll
        for (int i = 0; i < 4; i++) {
            int lin = tid + (i << 8);
            gl_lds16(asrc[i] + k0, As + lin * 8);
            gl_lds16(bsrc[i] + k0, Bs + lin * 8);
        }
        __syncthreads();
#pragma unroll
        for (int kk = 0; kk < 64; kk += 32) {
            s16x8 af[4], bf_[4];
#pragma unroll
            for (int m = 0; m < 4; m++)
                af[m] = lds_frag(As, wm*64 + m*16 + (lane & 15), (kk >> 3) + (lane >> 4));
#pragma unroll
            for (int n = 0; n < 4; n++)
                bf_[n] = lds_frag(Bs, wn*64 + n*16 + (lane & 15), (kk >> 3) + (lane >> 4));
#pragma unroll
            for (int m = 0; m < 4; m++)
#pragma unroll
                for (int n = 0; n < 4; n++)
                    acc[m][n] = __builtin_amdgcn_mfma_f32_16x16x32_bf16(af[m], bf_[n], acc[m][n], 0, 0, 0);
        }
    }
#pragma unroll
    for (int m = 0; m < 4; m++) {
#pragma unroll
        for (int j = 0; j < 4; j++) {
            int srow = row0 + wm*64 + m*16 + ((lane >> 4) << 2) + j;
            float g = gate[srow];
            float* yr = ybuf + (size_t)srow * D_DIM;
#pragma unroll
            for (int n = 0; n < 4; n++) {
                int c = n0 + wn*64 + n*16 + (lane & 15);
                yr[c] = g * (acc[m][n][j] + b2[e * D_DIM + c]);
            }
        }
    }
}

// out[t] = ybuf[slot1(t)] + ybuf[slot2(t)]   (one block per token, float4)
__global__ __launch_bounds__(256) void combine_kernel(const float* __restrict__ ybuf,
                                                      const int* __restrict__ slotof,
                                                      float* __restrict__ out) {
    int t = blockIdx.x;
    int s1 = slotof[t], s2 = slotof[T_TOK + t];
    const float4* y1 = (const float4*)(ybuf + (size_t)s1 * D_DIM);
    const float4* y2 = (const float4*)(ybuf + (size_t)s2 * D_DIM);
    float4* o = (float4*)(out + (size_t)t * D_DIM);
    int i = threadIdx.x;                              // 256 * 4 = 1024 = D
    float4 a = y1[i], b = y2[i];
    o[i] = make_float4(a.x + b.x, a.y + b.y, a.z + b.z, a.w + b.w);
}

// ---------------- host ----------------

extern "C" void kernel_launch(void* const* d_in, const int* in_sizes, int n_in,
                              void* d_out, int out_size, void* d_ws, size_t ws_size,
                              hipStream_t stream) {
    const float* x  = (const float*)d_in[0];
    const float* wr = (const float*)d_in[1];
    const float* br = (const float*)d_in[2];
    const float* w1 = (const float*)d_in[3];
    const float* b1 = (const float*)d_in[4];
    const float* w2 = (const float*)d_in[5];
    const float* b2 = (const float*)d_in[6];
    float* out = (float*)d_out;
    (void)in_sizes; (void)n_in; (void)ws_size; (void)out_size;

    char* ws = (char*)d_ws;
    size_t off = 0;
    auto alloc = [&](size_t bytes) { size_t o = off; off = (off + bytes + 1023) & ~(size_t)1023; return o; };
    size_t o_meta = alloc(256);                         // counts[8], counts2[8], poff[16]
    size_t o_list = alloc((size_t)ROWCAP * 4);
    size_t o_gate = alloc((size_t)ROWCAP * 4);
    size_t o_slot = alloc((size_t)2 * T_TOK * 4);
    size_t o_te   = alloc((size_t)2 * T_TOK * 4);
    size_t o_tg   = alloc((size_t)2 * T_TOK * 4);
    size_t o_xbf  = alloc((size_t)T_TOK * D_DIM * 2);
    size_t o_w1t  = alloc((size_t)NEXP * D_DIM * H_DIM * 2);
    size_t o_w2t  = alloc((size_t)NEXP * D_DIM * H_DIM * 2);
    size_t o_h    = alloc((size_t)ROWCAP * H_DIM * 2);
    size_t o_y    = alloc((size_t)ROWCAP * D_DIM * 4);

    int* counts  = (int*)(ws + o_meta);
    int* counts2 = counts + 8;
    int* poff    = counts + 16;
    int* list    = (int*)(ws + o_list);
    float* gate  = (float*)(ws + o_gate);
    int* slotof  = (int*)(ws + o_slot);
    int* te      = (int*)(ws + o_te);
    float* tg    = (float*)(ws + o_tg);
    unsigned short* xbf = (unsigned short*)(ws + o_xbf);
    unsigned short* w1t = (unsigned short*)(ws + o_w1t);
    unsigned short* w2t = (unsigned short*)(ws + o_w2t);
    unsigned short* hbuf = (unsigned short*)(ws + o_h);
    float* ybuf  = (float*)(ws + o_y);

    hipMemsetAsync(ws + o_meta, 0, 256, stream);
    hipMemsetAsync(ws + o_list, 0, (size_t)ROWCAP * 4, stream);   // pad slots gather token 0
    hipMemsetAsync(ws + o_gate, 0, (size_t)ROWCAP * 4, stream);   // pad slots gate 0.0

    // conversions
    convx_kernel<<<T_TOK * D_DIM / 4 / 256, 256, 0, stream>>>(x, xbf);
    convt_kernel<<<dim3(H_DIM / 32, D_DIM / 32, NEXP), dim3(32, 8), 0, stream>>>(w1, w1t, D_DIM, H_DIM);
    convt_kernel<<<dim3(D_DIM / 32, H_DIM / 32, NEXP), dim3(32, 8), 0, stream>>>(w2, w2t, H_DIM, D_DIM);

    // routing
    router_kernel<<<T_TOK / 4, 256, 0, stream>>>(x, wr, br, counts, te, tg);
    offsets_kernel<<<1, 64, 0, stream>>>(counts, poff);
    scatter_kernel<<<(2 * T_TOK) / 256, 256, 0, stream>>>(te, tg, counts2, poff, list, gate, slotof);

    // grouped GEMMs
    ffn1_kernel<<<dim3(ROWCAP / 128, H_DIM / 128), 256, 0, stream>>>(xbf, w1t, b1, hbuf, list, poff);
    ffn2_kernel<<<dim3(ROWCAP / 128, D_DIM / 128), 256, 0, stream>>>(hbuf, w2t, b2, ybuf, gate, poff);

    // gather-combine (fully writes out)
    combine_kernel<<<T_TOK, 256, 0, stream>>>(ybuf, slotof, out);
}